// Round 11
// baseline (156.957 us; speedup 1.0000x reference)
//
#include <hip/hip_runtime.h>

#define B_  4
#define T_  2048
#define C_  384
#define NH_ 6
#define HS_ 64
#define M_  (B_*T_)   // 8192 rows

typedef float floatx4 __attribute__((ext_vector_type(4)));
typedef __bf16 bf16x8 __attribute__((ext_vector_type(8)));
typedef unsigned short ushort_t;
typedef unsigned short ushortx8 __attribute__((ext_vector_type(8)));
typedef unsigned short ushortx4 __attribute__((ext_vector_type(4)));
typedef unsigned int uintx2 __attribute__((ext_vector_type(2)));

__device__ __forceinline__ ushort_t f2bf(float f) {   // RNE (epilogues)
    unsigned u = __builtin_bit_cast(unsigned, f);
    unsigned r = (u + 0x7FFFu + ((u >> 16) & 1u)) >> 16;
    return (ushort_t)r;
}
__device__ __forceinline__ unsigned f2bf_pk(float lo, float hi) {  // truncating pack
    return (__builtin_bit_cast(unsigned, lo) >> 16) |
           (__builtin_bit_cast(unsigned, hi) & 0xFFFF0000u);
}

// ---------------------------------------------------------------------------
// prep: x fp32->bf16 cast (blocks [0,1536)) + W transpose-casts ([1536,1680)).
// ---------------------------------------------------------------------------
__global__ __launch_bounds__(256) void prep(
    const float* __restrict__ x, ushort_t* __restrict__ xb,
    const float* __restrict__ Wq, const float* __restrict__ Wk,
    const float* __restrict__ Wv, const float* __restrict__ Wo,
    ushort_t* __restrict__ Wtq, ushort_t* __restrict__ Wtk,
    ushort_t* __restrict__ Wtv, ushort_t* __restrict__ Wto)
{
    __shared__ float Ls[64][65];
    const int tid = threadIdx.x;
    const int bx = blockIdx.x;

    if (bx < 1536) {
        const int i = (bx * 256 + tid) * 8;
        const float4 a = *(const float4*)&x[i];
        const float4 b = *(const float4*)&x[i + 4];
        ushortx8 p;
        p[0] = f2bf(a.x); p[1] = f2bf(a.y); p[2] = f2bf(a.z); p[3] = f2bf(a.w);
        p[4] = f2bf(b.x); p[5] = f2bf(b.y); p[6] = f2bf(b.z); p[7] = f2bf(b.w);
        *(ushortx8*)&xb[i] = p;
        return;
    }

    const int idx = bx - 1536;
    const int z = idx / 36, rest = idx % 36;
    const float* __restrict__ W = (z == 0) ? Wq : (z == 1) ? Wk : (z == 2) ? Wv : Wo;
    ushort_t* __restrict__ Wt   = (z == 0) ? Wtq : (z == 1) ? Wtk : (z == 2) ? Wtv : Wto;
    const int k0 = (rest / 6) * 64, n0 = (rest % 6) * 64;

    #pragma unroll
    for (int p = 0; p < 4; ++p) {
        const int kk = p * 16 + (tid >> 4);
        const int nn = (tid & 15) * 4;
        const float4 v = *(const float4*)&W[(size_t)(k0 + kk) * 384 + n0 + nn];
        Ls[kk][nn] = v.x; Ls[kk][nn + 1] = v.y; Ls[kk][nn + 2] = v.z; Ls[kk][nn + 3] = v.w;
    }
    __syncthreads();
    #pragma unroll
    for (int p = 0; p < 4; ++p) {
        const int n = p * 16 + (tid >> 4);
        const int kc = (tid & 15) * 4;
        ushortx4 pk;
        #pragma unroll
        for (int t = 0; t < 4; ++t) pk[t] = f2bf(Ls[kc + t][n]);
        *(ushortx4*)&Wt[(size_t)(n0 + n) * 384 + k0 + kc] = pk;
    }
}

// ---------------------------------------------------------------------------
// Fused QKV MFMA GEMM, BM=64(t) x BN=128(n): grid (128, 9). (unchanged R8)
// ---------------------------------------------------------------------------
__global__ __launch_bounds__(256) void qkv_gemm(
    const ushort_t* __restrict__ xb,
    const ushort_t* __restrict__ Wtq, const ushort_t* __restrict__ Wtk,
    const ushort_t* __restrict__ Wtv,
    const float* __restrict__ bq, const float* __restrict__ bk, const float* __restrict__ bv,
    ushort_t* __restrict__ Qb, ushort_t* __restrict__ Kb, ushort_t* __restrict__ Vtb)
{
    __shared__ ushort_t Sm[2][6144];

    const int tid  = threadIdx.x;
    const int lane = tid & 63;
    const int wv   = tid >> 6;
    const int m    = lane & 15;
    const int quad = lane >> 4;

    const int t0 = blockIdx.x * 64;
    const int n0 = blockIdx.y * 128;
    const int which = n0 / 384;
    const int n_in0 = n0 % 384;
    const bool isV = (which == 2);

    const ushort_t* __restrict__ Wt = (which == 0) ? Wtq : (which == 1) ? Wtk : Wtv;

    const int tg0 = (wv & 1) * 32;
    const int ng0 = (wv >> 1) * 64;

    const int rX = tid >> 2, cX = tid & 3;
    const int swX = ((cX ^ ((rX >> 1) & 3)) << 3);
    const int rW0 = tid >> 2, rW1 = rW0 + 64, cW = tid & 3;
    const int swW = ((cW ^ ((rW0 >> 1) & 3)) << 3);

    floatx4 acc[8];
    #pragma unroll
    for (int i = 0; i < 8; ++i) acc[i] = (floatx4){0.f, 0.f, 0.f, 0.f};

    ushortx8 xr  = *(const ushortx8*)&xb[(size_t)(t0 + rX) * 384 + cX * 8];
    ushortx8 wr0 = *(const ushortx8*)&Wt[(size_t)(n_in0 + rW0) * 384 + cW * 8];
    ushortx8 wr1 = *(const ushortx8*)&Wt[(size_t)(n_in0 + rW1) * 384 + cW * 8];

    for (int ks = 0; ks < 12; ++ks) {
        ushort_t* __restrict__ S = &Sm[ks & 1][0];
        *(ushortx8*)&S[rX * 32 + swX] = xr;
        *(ushortx8*)&S[2048 + rW0 * 32 + swW] = wr0;
        *(ushortx8*)&S[2048 + rW1 * 32 + swW] = wr1;
        __syncthreads();

        if (ks < 11) {
            const int kk = (ks + 1) * 32;
            xr  = *(const ushortx8*)&xb[(size_t)(t0 + rX) * 384 + kk + cX * 8];
            wr0 = *(const ushortx8*)&Wt[(size_t)(n_in0 + rW0) * 384 + kk + cW * 8];
            wr1 = *(const ushortx8*)&Wt[(size_t)(n_in0 + rW1) * 384 + kk + cW * 8];
        }

        bf16x8 fX[2], fW[4];
        #pragma unroll
        for (int i = 0; i < 2; ++i) {
            const int r = tg0 + i * 16 + m;
            fX[i] = *(const bf16x8*)&S[r * 32 + ((quad ^ ((r >> 1) & 3)) << 3)];
        }
        #pragma unroll
        for (int i = 0; i < 4; ++i) {
            const int r = ng0 + i * 16 + m;
            fW[i] = *(const bf16x8*)&S[2048 + r * 32 + ((quad ^ ((r >> 1) & 3)) << 3)];
        }
        if (isV) {
            #pragma unroll
            for (int i = 0; i < 2; ++i)
                #pragma unroll
                for (int j = 0; j < 4; ++j)
                    acc[i * 4 + j] = __builtin_amdgcn_mfma_f32_16x16x32_bf16(fX[i], fW[j], acc[i * 4 + j], 0, 0, 0);
        } else {
            #pragma unroll
            for (int i = 0; i < 4; ++i)
                #pragma unroll
                for (int j = 0; j < 2; ++j)
                    acc[i * 2 + j] = __builtin_amdgcn_mfma_f32_16x16x32_bf16(fW[i], fX[j], acc[i * 2 + j], 0, 0, 0);
        }
    }

    if (!isV) {
        ushort_t* __restrict__ out = (which == 0) ? Qb : Kb;
        const float* __restrict__ bias = (which == 0) ? bq : bk;
        const float scale = (which == 0) ? 0.125f : 1.0f;
        #pragma unroll
        for (int i = 0; i < 4; ++i) {
            const int n_base = n_in0 + ng0 + i * 16 + quad * 4;
            const int h = n_base >> 6, d0 = n_base & 63;
            #pragma unroll
            for (int j = 0; j < 2; ++j) {
                const int tg = t0 + tg0 + j * 16 + m;
                const int b = tg >> 11, tb = tg & (T_ - 1);
                ushortx4 pk;
                #pragma unroll
                for (int r = 0; r < 4; ++r)
                    pk[r] = f2bf((acc[i * 2 + j][r] + bias[n_base + r]) * scale);
                *(ushortx4*)&out[(((size_t)(b * NH_ + h)) * T_ + tb) * HS_ + d0] = pk;
            }
        }
    } else {
        #pragma unroll
        for (int i = 0; i < 2; ++i) {
            const int tgq = t0 + tg0 + i * 16 + quad * 4;
            const int b = tgq >> 11, tb0 = tgq & (T_ - 1);
            #pragma unroll
            for (int j = 0; j < 4; ++j) {
                const int n_l = n_in0 + ng0 + j * 16 + m;
                const int h = n_l >> 6, d = n_l & 63;
                const float bb = bv[n_l];
                ushortx4 pk;
                #pragma unroll
                for (int r = 0; r < 4; ++r) pk[r] = f2bf(acc[i * 4 + j][r] + bb);
                *(ushortx4*)&Vtb[(((size_t)(b * NH_ + h)) * HS_ + d) * T_ + tb0] = pk;
            }
        }
    }
}

// ---------------------------------------------------------------------------
// Output projection, BM=64 x BN=64 (768 blocks). (unchanged R8)
// ---------------------------------------------------------------------------
__global__ __launch_bounds__(256) void proj_gemm(
    const ushort_t* __restrict__ ctxb,
    const ushort_t* __restrict__ Wto,
    const float* __restrict__ bo,
    float* __restrict__ out)
{
    __shared__ ushort_t Sm[2][4096];

    const int tid  = threadIdx.x;
    const int lane = tid & 63;
    const int wv   = tid >> 6;
    const int m    = lane & 15;
    const int quad = lane >> 4;

    const int t0 = blockIdx.x * 64;
    const int n0 = blockIdx.y * 64;
    const int tg0 = (wv & 1) * 32;
    const int ng0 = (wv >> 1) * 32;

    const int rC = tid >> 2, cC = tid & 3;
    const int swC = ((cC ^ ((rC >> 1) & 3)) << 3);

    floatx4 acc[2][2];
    #pragma unroll
    for (int i = 0; i < 2; ++i)
        #pragma unroll
        for (int j = 0; j < 2; ++j) acc[i][j] = (floatx4){0.f, 0.f, 0.f, 0.f};

    ushortx8 cr = *(const ushortx8*)&ctxb[(size_t)(t0 + rC) * 384 + cC * 8];
    ushortx8 wr = *(const ushortx8*)&Wto[(size_t)(n0 + rC) * 384 + cC * 8];

    for (int ks = 0; ks < 12; ++ks) {
        ushort_t* __restrict__ S = &Sm[ks & 1][0];
        *(ushortx8*)&S[rC * 32 + swC] = cr;
        *(ushortx8*)&S[2048 + rC * 32 + swC] = wr;
        __syncthreads();

        if (ks < 11) {
            const int kk = (ks + 1) * 32;
            cr = *(const ushortx8*)&ctxb[(size_t)(t0 + rC) * 384 + kk + cC * 8];
            wr = *(const ushortx8*)&Wto[(size_t)(n0 + rC) * 384 + kk + cC * 8];
        }

        bf16x8 fA[2], fB[2];
        #pragma unroll
        for (int i = 0; i < 2; ++i) {
            const int rn = ng0 + i * 16 + m;
            fA[i] = *(const bf16x8*)&S[2048 + rn * 32 + ((quad ^ ((rn >> 1) & 3)) << 3)];
            const int rt = tg0 + i * 16 + m;
            fB[i] = *(const bf16x8*)&S[rt * 32 + ((quad ^ ((rt >> 1) & 3)) << 3)];
        }
        #pragma unroll
        for (int i = 0; i < 2; ++i)
            #pragma unroll
            for (int j = 0; j < 2; ++j)
                acc[i][j] = __builtin_amdgcn_mfma_f32_16x16x32_bf16(fA[i], fB[j], acc[i][j], 0, 0, 0);
    }

    #pragma unroll
    for (int i = 0; i < 2; ++i) {
        const int n_base = n0 + ng0 + i * 16 + quad * 4;
        const float4 bb = *(const float4*)&bo[n_base];
        #pragma unroll
        for (int j = 0; j < 2; ++j) {
            const int tg = t0 + tg0 + j * 16 + m;
            float4 o;
            o.x = acc[i][j][0] + bb.x;
            o.y = acc[i][j][1] + bb.y;
            o.z = acc[i][j][2] + bb.z;
            o.w = acc[i][j][3] + bb.w;
            *(float4*)&out[(size_t)tg * 384 + n_base] = o;
        }
    }
}

// ---------------------------------------------------------------------------
// MFMA flash attention: 128 q-rows/block, 4 waves x 32 rows (rt0 = lower
// 64-half, rt1 = upper). K/V fragments are read from LDS ONCE per wave per
// tile and reused for both row-tiles (2 live regs, read-2-use-4 -> no VGPR
// blowup). All 4 waves compute every tile (keeps 12 active waves/CU, unlike
// R9's parity split). rt0 skips the final tile (all its keys are future).
// Transposed compute (S^T/O^T), packed P writes (2 regions/wave), single
// barrier, double-buffered swizzled staging -- all identical to R10.
// Grid: 384 blocks (16 j x 24 bh), heavy-first; dynamic backfill balances.
// ---------------------------------------------------------------------------
__global__ __launch_bounds__(256) void attn_mfma(
    const ushort_t* __restrict__ Q,    // [BH][T][64] bf16, pre-scaled 1/8
    const ushort_t* __restrict__ K,    // [BH][T][64] bf16
    const ushort_t* __restrict__ Vt,   // [BH][64][T] bf16
    ushort_t* __restrict__ ctx)        // [B][T][C] bf16
{
    __shared__ ushort_t Ks[2][64 * 64];
    __shared__ ushort_t Vs[2][64 * 64];
    __shared__ ushort_t Ps[4][2][16 * 64];   // per-wave, per-row-tile

    const int tid  = threadIdx.x;
    const int lane = tid & 63;
    const int wv   = tid >> 6;
    const int m    = lane & 15;
    const int quad = lane >> 4;
    const int cA   = (quad ^ (m & 7)) << 3;

    const int bx = blockIdx.x;            // 0..383, heavy first
    const int j  = 15 - (bx / 24);
    const int bh = bx % 24;
    const int b  = bh / 6, h = bh % 6;

    const int ext  = 2 * j + 1;           // last 64-key tile (rt1's diagonal)
    const int qloc = wv * 16 + m;         // q offset within any diagonal tile

    const ushort_t* __restrict__ Kg = K  + (size_t)bh * (T_ * HS_);
    const ushort_t* __restrict__ Vg = Vt + (size_t)bh * (HS_ * T_);

    const int r0 = tid >> 3,         c0 = tid & 7;
    const int r1 = (tid + 256) >> 3, c1 = tid & 7;
    const int sw0 = ((c0 ^ (r0 & 7)) << 3);
    const int sw1 = ((c1 ^ (r1 & 7)) << 3);

    // Q A-frags per row-tile: rows j*128 + rt*64 + wv*16 + m
    bf16x8 qf[2][2];
    #pragma unroll
    for (int rt = 0; rt < 2; ++rt) {
        const ushort_t* qp = Q + ((size_t)bh * T_ + (j * 128 + rt * 64 + wv * 16 + m)) * HS_;
        qf[rt][0] = *(const bf16x8*)(qp + quad * 8);
        qf[rt][1] = *(const bf16x8*)(qp + 32 + quad * 8);
    }

    floatx4 acc_o[2][4];
    #pragma unroll
    for (int rt = 0; rt < 2; ++rt)
        #pragma unroll
        for (int dt = 0; dt < 4; ++dt) acc_o[rt][dt] = (floatx4){0.f, 0.f, 0.f, 0.f};
    float l_lane[2] = {0.f, 0.f};

    ushort_t* __restrict__ Pw0 = &Ps[wv][0][0];
    ushort_t* __restrict__ Pw1 = &Ps[wv][1][0];
    const int pbase = m * 64 + ((quad & 1) << 2);
    const int pcs   = (quad >> 1);
    const int pxor  = m & 7;

    ushortx8 kr0 = *(const ushortx8*)&Kg[(size_t)r0 * HS_ + c0 * 8];
    ushortx8 kr1 = *(const ushortx8*)&Kg[(size_t)r1 * HS_ + c1 * 8];
    ushortx8 vr0 = *(const ushortx8*)&Vg[(size_t)r0 * T_ + c0 * 8];
    ushortx8 vr1 = *(const ushortx8*)&Vg[(size_t)r1 * T_ + c1 * 8];

    for (int kt = 0; kt <= ext; ++kt) {
        ushort_t* __restrict__ Kc = &Ks[kt & 1][0];
        ushort_t* __restrict__ Vc = &Vs[kt & 1][0];
        *(ushortx8*)&Kc[r0 * 64 + sw0] = kr0;
        *(ushortx8*)&Kc[r1 * 64 + sw1] = kr1;
        *(ushortx8*)&Vc[r0 * 64 + sw0] = vr0;
        *(ushortx8*)&Vc[r1 * 64 + sw1] = vr1;
        __syncthreads();

        if (kt < ext) {   // prefetch after barrier; hides under compute
            const int s1 = (kt + 1) * 64;
            kr0 = *(const ushortx8*)&Kg[(size_t)(s1 + r0) * HS_ + c0 * 8];
            kr1 = *(const ushortx8*)&Kg[(size_t)(s1 + r1) * HS_ + c1 * 8];
            vr0 = *(const ushortx8*)&Vg[(size_t)r0 * T_ + s1 + c0 * 8];
            vr1 = *(const ushortx8*)&Vg[(size_t)r1 * T_ + s1 + c1 * 8];
        }

        const bool do0 = (kt < ext);          // rt0's keys end at tile ext-1

        // ---- S^T = K Q^T : K-frags read once, used for both row-tiles ----
        floatx4 st0[4], st1[4];
        #pragma unroll
        for (int kc = 0; kc < 4; ++kc) {
            const int kb = (kc * 16 + m) * 64;
            bf16x8 k0 = *(const bf16x8*)&Kc[kb + cA];
            bf16x8 k1 = *(const bf16x8*)&Kc[kb + (cA ^ 32)];
            if (do0) {
                floatx4 a = (floatx4){0.f, 0.f, 0.f, 0.f};
                a = __builtin_amdgcn_mfma_f32_16x16x32_bf16(k0, qf[0][0], a, 0, 0, 0);
                a = __builtin_amdgcn_mfma_f32_16x16x32_bf16(k1, qf[0][1], a, 0, 0, 0);
                st0[kc] = a;
            }
            floatx4 a1 = (floatx4){0.f, 0.f, 0.f, 0.f};
            a1 = __builtin_amdgcn_mfma_f32_16x16x32_bf16(k0, qf[1][0], a1, 0, 0, 0);
            a1 = __builtin_amdgcn_mfma_f32_16x16x32_bf16(k1, qf[1][1], a1, 0, 0, 0);
            st1[kc] = a1;
        }

        // causal masks: rt0 diag at kt==ext-1, rt1 diag at kt==ext
        if (kt == ext - 1) {
            #pragma unroll
            for (int kc = 0; kc < 4; ++kc)
                #pragma unroll
                for (int r = 0; r < 4; ++r)
                    if (kc * 16 + quad * 4 + r > qloc) st0[kc][r] = -1e30f;
        }
        if (kt == ext) {
            #pragma unroll
            for (int kc = 0; kc < 4; ++kc)
                #pragma unroll
                for (int r = 0; r < 4; ++r)
                    if (kc * 16 + quad * 4 + r > qloc) st1[kc][r] = -1e30f;
        }

        // ---- softmax + packed P writes (per row-tile region) ----
        if (do0) {
            float lsum = 0.f;
            #pragma unroll
            for (int kc = 0; kc < 4; ++kc) {
                const float p0 = __expf(st0[kc][0]);
                const float p1 = __expf(st0[kc][1]);
                const float p2 = __expf(st0[kc][2]);
                const float p3 = __expf(st0[kc][3]);
                lsum += (p0 + p1) + (p2 + p3);
                uintx2 pk;
                pk[0] = f2bf_pk(p0, p1);
                pk[1] = f2bf_pk(p2, p3);
                *(uintx2*)&Pw0[pbase + (((kc * 2 + pcs) ^ pxor) << 3)] = pk;
            }
            l_lane[0] += lsum;
        }
        {
            float lsum = 0.f;
            #pragma unroll
            for (int kc = 0; kc < 4; ++kc) {
                const float p0 = __expf(st1[kc][0]);
                const float p1 = __expf(st1[kc][1]);
                const float p2 = __expf(st1[kc][2]);
                const float p3 = __expf(st1[kc][3]);
                lsum += (p0 + p1) + (p2 + p3);
                uintx2 pk;
                pk[0] = f2bf_pk(p0, p1);
                pk[1] = f2bf_pk(p2, p3);
                *(uintx2*)&Pw1[pbase + (((kc * 2 + pcs) ^ pxor) << 3)] = pk;
            }
            l_lane[1] += lsum;
        }

        asm volatile("s_waitcnt lgkmcnt(0)" ::: "memory");
        bf16x8 pf00, pf01, pf10, pf11;
        if (do0) {
            pf00 = *(const bf16x8*)&Pw0[m * 64 + cA];
            pf01 = *(const bf16x8*)&Pw0[m * 64 + (cA ^ 32)];
        }
        pf10 = *(const bf16x8*)&Pw1[m * 64 + cA];
        pf11 = *(const bf16x8*)&Pw1[m * 64 + (cA ^ 32)];

        // ---- O^T += V^T P^T : V-frags read once, used for both row-tiles ----
        #pragma unroll
        for (int dt = 0; dt < 4; ++dt) {
            const int vb = (dt * 16 + m) * 64;
            bf16x8 v0 = *(const bf16x8*)&Vc[vb + cA];
            bf16x8 v1 = *(const bf16x8*)&Vc[vb + (cA ^ 32)];
            if (do0) {
                acc_o[0][dt] = __builtin_amdgcn_mfma_f32_16x16x32_bf16(v0, pf00, acc_o[0][dt], 0, 0, 0);
                acc_o[0][dt] = __builtin_amdgcn_mfma_f32_16x16x32_bf16(v1, pf01, acc_o[0][dt], 0, 0, 0);
            }
            acc_o[1][dt] = __builtin_amdgcn_mfma_f32_16x16x32_bf16(v0, pf10, acc_o[1][dt], 0, 0, 0);
            acc_o[1][dt] = __builtin_amdgcn_mfma_f32_16x16x32_bf16(v1, pf11, acc_o[1][dt], 0, 0, 0);
        }
    }

    // epilogue per row-tile: reduce l over quads, store O^T columns
    #pragma unroll
    for (int rt = 0; rt < 2; ++rt) {
        float ls = l_lane[rt];
        ls += __shfl_xor(ls, 16, 64);
        ls += __shfl_xor(ls, 32, 64);
        const float rcp = 1.0f / ls;

        const int t = j * 128 + rt * 64 + wv * 16 + m;
        ushort_t* __restrict__ cp = ctx + ((size_t)(b * T_) + t) * C_ + h * HS_ + quad * 4;
        #pragma unroll
        for (int dt = 0; dt < 4; ++dt) {
            ushortx4 pk;
            #pragma unroll
            for (int r = 0; r < 4; ++r) pk[r] = f2bf(acc_o[rt][dt][r] * rcp);
            *(ushortx4*)&cp[dt * 16] = pk;
        }
    }
}

// ---------------------------------------------------------------------------
// Launcher. ws (ushorts): xb | Wtq|Wtk|Wtv|Wto | Q | K | Vt | ctx  (~32 MB)
// ---------------------------------------------------------------------------
extern "C" void kernel_launch(void* const* d_in, const int* in_sizes, int n_in,
                              void* d_out, int out_size, void* d_ws, size_t ws_size,
                              hipStream_t stream) {
    const float* x  = (const float*)d_in[0];
    const float* Wq = (const float*)d_in[1];
    const float* bq = (const float*)d_in[2];
    const float* Wk = (const float*)d_in[3];
    const float* bk = (const float*)d_in[4];
    const float* Wv = (const float*)d_in[5];
    const float* bv = (const float*)d_in[6];
    const float* Wo = (const float*)d_in[7];
    const float* bo = (const float*)d_in[8];
    float* out = (float*)d_out;

    const size_t per = (size_t)B_ * NH_ * T_ * HS_;  // 3,145,728
    const size_t wsz = 384 * 384;                    // 147,456
    ushort_t* xb  = (ushort_t*)d_ws;
    ushort_t* Wtq = xb + per;
    ushort_t* Wtk = Wtq + wsz;
    ushort_t* Wtv = Wtk + wsz;
    ushort_t* Wto = Wtv + wsz;
    ushort_t* Qb  = Wto + wsz;
    ushort_t* Kb  = Qb + per;
    ushort_t* Vtb = Kb + per;
    ushort_t* ctxb = Vtb + per;

    prep<<<dim3(1536 + 144), 256, 0, stream>>>(
        x, xb, Wq, Wk, Wv, Wo, Wtq, Wtk, Wtv, Wto);

    qkv_gemm<<<dim3(M_ / 64, 1152 / 128), 256, 0, stream>>>(
        xb, Wtq, Wtk, Wtv, bq, bk, bv, Qb, Kb, Vtb);

    attn_mfma<<<dim3(384), 256, 0, stream>>>(Qb, Kb, Vtb, ctxb);

    proj_gemm<<<dim3(M_ / 64, 384 / 64), 256, 0, stream>>>(ctxb, Wto, bo, out);
}

// Round 12
// 140.267 us; speedup vs baseline: 1.1190x; 1.1190x over previous
//
#include <hip/hip_runtime.h>

#define B_  4
#define T_  2048
#define C_  384
#define NH_ 6
#define HS_ 64
#define M_  (B_*T_)   // 8192 rows

typedef float floatx4 __attribute__((ext_vector_type(4)));
typedef __bf16 bf16x8 __attribute__((ext_vector_type(8)));
typedef unsigned short ushort_t;
typedef unsigned short ushortx8 __attribute__((ext_vector_type(8)));
typedef unsigned short ushortx4 __attribute__((ext_vector_type(4)));
typedef unsigned int uintx2 __attribute__((ext_vector_type(2)));

__device__ __forceinline__ ushort_t f2bf(float f) {   // RNE
    unsigned u = __builtin_bit_cast(unsigned, f);
    unsigned r = (u + 0x7FFFu + ((u >> 16) & 1u)) >> 16;
    return (ushort_t)r;
}
__device__ __forceinline__ unsigned f2bf_pk(float lo, float hi) {  // truncating pack
    return (__builtin_bit_cast(unsigned, lo) >> 16) |
           (__builtin_bit_cast(unsigned, hi) & 0xFFFF0000u);
}

// ---------------------------------------------------------------------------
// prep: W transpose-casts ONLY (x is cast on the fly inside qkv staging).
// 4 matrices x 36 tiles = 144 blocks.
// ---------------------------------------------------------------------------
__global__ __launch_bounds__(256) void prep(
    const float* __restrict__ Wq, const float* __restrict__ Wk,
    const float* __restrict__ Wv, const float* __restrict__ Wo,
    ushort_t* __restrict__ Wtq, ushort_t* __restrict__ Wtk,
    ushort_t* __restrict__ Wtv, ushort_t* __restrict__ Wto)
{
    __shared__ float Ls[64][65];
    const int tid = threadIdx.x;
    const int idx = blockIdx.x;
    const int z = idx / 36, rest = idx % 36;
    const float* __restrict__ W = (z == 0) ? Wq : (z == 1) ? Wk : (z == 2) ? Wv : Wo;
    ushort_t* __restrict__ Wt   = (z == 0) ? Wtq : (z == 1) ? Wtk : (z == 2) ? Wtv : Wto;
    const int k0 = (rest / 6) * 64, n0 = (rest % 6) * 64;

    #pragma unroll
    for (int p = 0; p < 4; ++p) {
        const int kk = p * 16 + (tid >> 4);
        const int nn = (tid & 15) * 4;
        const float4 v = *(const float4*)&W[(size_t)(k0 + kk) * 384 + n0 + nn];
        Ls[kk][nn] = v.x; Ls[kk][nn + 1] = v.y; Ls[kk][nn + 2] = v.z; Ls[kk][nn + 3] = v.w;
    }
    __syncthreads();
    #pragma unroll
    for (int p = 0; p < 4; ++p) {
        const int n = p * 16 + (tid >> 4);
        const int kc = (tid & 15) * 4;
        ushortx4 pk;
        #pragma unroll
        for (int t = 0; t < 4; ++t) pk[t] = f2bf(Ls[kc + t][n]);
        *(ushortx4*)&Wt[(size_t)(n0 + n) * 384 + k0 + kc] = pk;
    }
}

// ---------------------------------------------------------------------------
// Fused QKV MFMA GEMM, BM=64(t) x BN=128(n): grid (128, 9).
// x is staged DIRECTLY from fp32 with RNE cast (no separate cast pass).
// Single-barrier pipeline, double-buffered swizzled LDS (R8 structure).
// ---------------------------------------------------------------------------
__global__ __launch_bounds__(256) void qkv_gemm(
    const float* __restrict__ x,
    const ushort_t* __restrict__ Wtq, const ushort_t* __restrict__ Wtk,
    const ushort_t* __restrict__ Wtv,
    const float* __restrict__ bq, const float* __restrict__ bk, const float* __restrict__ bv,
    ushort_t* __restrict__ Qb, ushort_t* __restrict__ Kb, ushort_t* __restrict__ Vtb)
{
    __shared__ ushort_t Sm[2][6144];

    const int tid  = threadIdx.x;
    const int lane = tid & 63;
    const int wv   = tid >> 6;
    const int m    = lane & 15;
    const int quad = lane >> 4;

    const int t0 = blockIdx.x * 64;
    const int n0 = blockIdx.y * 128;
    const int which = n0 / 384;
    const int n_in0 = n0 % 384;
    const bool isV = (which == 2);

    const ushort_t* __restrict__ Wt = (which == 0) ? Wtq : (which == 1) ? Wtk : Wtv;

    const int tg0 = (wv & 1) * 32;
    const int ng0 = (wv >> 1) * 64;

    const int rX = tid >> 2, cX = tid & 3;
    const int swX = ((cX ^ ((rX >> 1) & 3)) << 3);
    const int rW0 = tid >> 2, rW1 = rW0 + 64, cW = tid & 3;
    const int swW = ((cW ^ ((rW0 >> 1) & 3)) << 3);

    floatx4 acc[8];
    #pragma unroll
    for (int i = 0; i < 8; ++i) acc[i] = (floatx4){0.f, 0.f, 0.f, 0.f};

    // prologue: k-slab 0 -> regs (x as fp32 pair)
    float4 xa = *(const float4*)&x[(size_t)(t0 + rX) * 384 + cX * 8];
    float4 xb4 = *(const float4*)&x[(size_t)(t0 + rX) * 384 + cX * 8 + 4];
    ushortx8 wr0 = *(const ushortx8*)&Wt[(size_t)(n_in0 + rW0) * 384 + cW * 8];
    ushortx8 wr1 = *(const ushortx8*)&Wt[(size_t)(n_in0 + rW1) * 384 + cW * 8];

    for (int ks = 0; ks < 12; ++ks) {
        ushort_t* __restrict__ S = &Sm[ks & 1][0];
        {
            ushortx8 xp;
            xp[0] = f2bf(xa.x); xp[1] = f2bf(xa.y); xp[2] = f2bf(xa.z); xp[3] = f2bf(xa.w);
            xp[4] = f2bf(xb4.x); xp[5] = f2bf(xb4.y); xp[6] = f2bf(xb4.z); xp[7] = f2bf(xb4.w);
            *(ushortx8*)&S[rX * 32 + swX] = xp;
        }
        *(ushortx8*)&S[2048 + rW0 * 32 + swW] = wr0;
        *(ushortx8*)&S[2048 + rW1 * 32 + swW] = wr1;
        __syncthreads();

        if (ks < 11) {   // prefetch AFTER barrier; latency hides under compute
            const int kk = (ks + 1) * 32;
            xa  = *(const float4*)&x[(size_t)(t0 + rX) * 384 + kk + cX * 8];
            xb4 = *(const float4*)&x[(size_t)(t0 + rX) * 384 + kk + cX * 8 + 4];
            wr0 = *(const ushortx8*)&Wt[(size_t)(n_in0 + rW0) * 384 + kk + cW * 8];
            wr1 = *(const ushortx8*)&Wt[(size_t)(n_in0 + rW1) * 384 + kk + cW * 8];
        }

        bf16x8 fX[2], fW[4];
        #pragma unroll
        for (int i = 0; i < 2; ++i) {
            const int r = tg0 + i * 16 + m;
            fX[i] = *(const bf16x8*)&S[r * 32 + ((quad ^ ((r >> 1) & 3)) << 3)];
        }
        #pragma unroll
        for (int i = 0; i < 4; ++i) {
            const int r = ng0 + i * 16 + m;
            fW[i] = *(const bf16x8*)&S[2048 + r * 32 + ((quad ^ ((r >> 1) & 3)) << 3)];
        }
        if (isV) {
            #pragma unroll
            for (int i = 0; i < 2; ++i)
                #pragma unroll
                for (int j = 0; j < 4; ++j)
                    acc[i * 4 + j] = __builtin_amdgcn_mfma_f32_16x16x32_bf16(fX[i], fW[j], acc[i * 4 + j], 0, 0, 0);
        } else {
            #pragma unroll
            for (int i = 0; i < 4; ++i)
                #pragma unroll
                for (int j = 0; j < 2; ++j)
                    acc[i * 2 + j] = __builtin_amdgcn_mfma_f32_16x16x32_bf16(fW[i], fX[j], acc[i * 2 + j], 0, 0, 0);
        }
    }

    if (!isV) {
        ushort_t* __restrict__ out = (which == 0) ? Qb : Kb;
        const float* __restrict__ bias = (which == 0) ? bq : bk;
        const float scale = (which == 0) ? 0.125f : 1.0f;
        #pragma unroll
        for (int i = 0; i < 4; ++i) {
            const int n_base = n_in0 + ng0 + i * 16 + quad * 4;
            const int h = n_base >> 6, d0 = n_base & 63;
            #pragma unroll
            for (int j = 0; j < 2; ++j) {
                const int tg = t0 + tg0 + j * 16 + m;
                const int b = tg >> 11, tb = tg & (T_ - 1);
                ushortx4 pk;
                #pragma unroll
                for (int r = 0; r < 4; ++r)
                    pk[r] = f2bf((acc[i * 2 + j][r] + bias[n_base + r]) * scale);
                *(ushortx4*)&out[(((size_t)(b * NH_ + h)) * T_ + tb) * HS_ + d0] = pk;
            }
        }
    } else {
        #pragma unroll
        for (int i = 0; i < 2; ++i) {
            const int tgq = t0 + tg0 + i * 16 + quad * 4;
            const int b = tgq >> 11, tb0 = tgq & (T_ - 1);
            #pragma unroll
            for (int j = 0; j < 4; ++j) {
                const int n_l = n_in0 + ng0 + j * 16 + m;
                const int h = n_l >> 6, d = n_l & 63;
                const float bb = bv[n_l];
                ushortx4 pk;
                #pragma unroll
                for (int r = 0; r < 4; ++r) pk[r] = f2bf(acc[i * 4 + j][r] + bb);
                *(ushortx4*)&Vtb[(((size_t)(b * NH_ + h)) * HS_ + d) * T_ + tb0] = pk;
            }
        }
    }
}

// ---------------------------------------------------------------------------
// Output projection, BM=64 x BN=64 (768 blocks). (unchanged)
// ---------------------------------------------------------------------------
__global__ __launch_bounds__(256) void proj_gemm(
    const ushort_t* __restrict__ ctxb,
    const ushort_t* __restrict__ Wto,
    const float* __restrict__ bo,
    float* __restrict__ out)
{
    __shared__ ushort_t Sm[2][4096];

    const int tid  = threadIdx.x;
    const int lane = tid & 63;
    const int wv   = tid >> 6;
    const int m    = lane & 15;
    const int quad = lane >> 4;

    const int t0 = blockIdx.x * 64;
    const int n0 = blockIdx.y * 64;
    const int tg0 = (wv & 1) * 32;
    const int ng0 = (wv >> 1) * 32;

    const int rC = tid >> 2, cC = tid & 3;
    const int swC = ((cC ^ ((rC >> 1) & 3)) << 3);

    floatx4 acc[2][2];
    #pragma unroll
    for (int i = 0; i < 2; ++i)
        #pragma unroll
        for (int j = 0; j < 2; ++j) acc[i][j] = (floatx4){0.f, 0.f, 0.f, 0.f};

    ushortx8 cr = *(const ushortx8*)&ctxb[(size_t)(t0 + rC) * 384 + cC * 8];
    ushortx8 wr = *(const ushortx8*)&Wto[(size_t)(n0 + rC) * 384 + cC * 8];

    for (int ks = 0; ks < 12; ++ks) {
        ushort_t* __restrict__ S = &Sm[ks & 1][0];
        *(ushortx8*)&S[rC * 32 + swC] = cr;
        *(ushortx8*)&S[2048 + rC * 32 + swC] = wr;
        __syncthreads();

        if (ks < 11) {
            const int kk = (ks + 1) * 32;
            cr = *(const ushortx8*)&ctxb[(size_t)(t0 + rC) * 384 + kk + cC * 8];
            wr = *(const ushortx8*)&Wto[(size_t)(n0 + rC) * 384 + kk + cC * 8];
        }

        bf16x8 fA[2], fB[2];
        #pragma unroll
        for (int i = 0; i < 2; ++i) {
            const int rn = ng0 + i * 16 + m;
            fA[i] = *(const bf16x8*)&S[2048 + rn * 32 + ((quad ^ ((rn >> 1) & 3)) << 3)];
            const int rt = tg0 + i * 16 + m;
            fB[i] = *(const bf16x8*)&S[rt * 32 + ((quad ^ ((rt >> 1) & 3)) << 3)];
        }
        #pragma unroll
        for (int i = 0; i < 2; ++i)
            #pragma unroll
            for (int j = 0; j < 2; ++j)
                acc[i][j] = __builtin_amdgcn_mfma_f32_16x16x32_bf16(fA[i], fB[j], acc[i][j], 0, 0, 0);
    }

    #pragma unroll
    for (int i = 0; i < 2; ++i) {
        const int n_base = n0 + ng0 + i * 16 + quad * 4;
        const float4 bb = *(const float4*)&bo[n_base];
        #pragma unroll
        for (int j = 0; j < 2; ++j) {
            const int tg = t0 + tg0 + j * 16 + m;
            float4 o;
            o.x = acc[i][j][0] + bb.x;
            o.y = acc[i][j][1] + bb.y;
            o.z = acc[i][j][2] + bb.z;
            o.w = acc[i][j][3] + bb.w;
            *(float4*)&out[(size_t)tg * 384 + n_base] = o;
        }
    }
}

// ---------------------------------------------------------------------------
// MFMA flash attention — EXACT R10 structure (the validated 33 µs config):
// 64 q-rows/block, 4 waves x 16 rows, uniform extent j, snake rank balance,
// transposed compute (S^T/O^T), packed P b64 writes, scalar l per lane,
// double-buffered swizzled staging, single barrier per tile.
// ---------------------------------------------------------------------------
__global__ __launch_bounds__(256) void attn_mfma(
    const ushort_t* __restrict__ Q,    // [BH][T][64] bf16, pre-scaled 1/8
    const ushort_t* __restrict__ K,    // [BH][T][64] bf16
    const ushort_t* __restrict__ Vt,   // [BH][64][T] bf16
    ushort_t* __restrict__ ctx)        // [B][T][C] bf16
{
    __shared__ ushort_t Ks[2][64 * 64];
    __shared__ ushort_t Vs[2][64 * 64];
    __shared__ ushort_t Ps[4][16 * 64];

    const int tid  = threadIdx.x;
    const int lane = tid & 63;
    const int wv   = tid >> 6;
    const int m    = lane & 15;
    const int quad = lane >> 4;
    const int cA   = (quad ^ (m & 7)) << 3;

    const int flat = blockIdx.x + 32 * (blockIdx.y + 6 * blockIdx.z);  // 0..767
    const int rr = flat >> 8, ss = flat & 255;
    const int rank = (rr << 8) + ((rr & 1) ? (255 - ss) : ss);
    const int j   = 31 - (rank / 24);
    const int idx = rank % 24;
    const int b   = idx / 6, h = idx % 6;
    const int bh  = idx;

    const int rowbase = j * 64 + wv * 16;
    const int ext = j;
    const int qloc = wv * 16 + m;

    const ushort_t* __restrict__ Kg = K  + (size_t)bh * (T_ * HS_);
    const ushort_t* __restrict__ Vg = Vt + (size_t)bh * (HS_ * T_);

    const int r0 = tid >> 3,         c0 = tid & 7;
    const int r1 = (tid + 256) >> 3, c1 = tid & 7;
    const int sw0 = ((c0 ^ (r0 & 7)) << 3);
    const int sw1 = ((c1 ^ (r1 & 7)) << 3);

    bf16x8 qf0, qf1;
    {
        const ushort_t* qp = Q + ((size_t)bh * T_ + rowbase + m) * HS_;
        qf0 = *(const bf16x8*)(qp + quad * 8);
        qf1 = *(const bf16x8*)(qp + 32 + quad * 8);
    }

    floatx4 acc_o[4];
    #pragma unroll
    for (int dt = 0; dt < 4; ++dt) acc_o[dt] = (floatx4){0.f, 0.f, 0.f, 0.f};
    float l_lane = 0.f;

    ushort_t* __restrict__ Pw = &Ps[wv][0];
    const int pbase = m * 64 + ((quad & 1) << 2);
    const int pcs   = (quad >> 1);
    const int pxor  = m & 7;

    ushortx8 kr0 = *(const ushortx8*)&Kg[(size_t)r0 * HS_ + c0 * 8];
    ushortx8 kr1 = *(const ushortx8*)&Kg[(size_t)r1 * HS_ + c1 * 8];
    ushortx8 vr0 = *(const ushortx8*)&Vg[(size_t)r0 * T_ + c0 * 8];
    ushortx8 vr1 = *(const ushortx8*)&Vg[(size_t)r1 * T_ + c1 * 8];

    for (int kt = 0; kt <= ext; ++kt) {
        ushort_t* __restrict__ Kc = &Ks[kt & 1][0];
        ushort_t* __restrict__ Vc = &Vs[kt & 1][0];
        *(ushortx8*)&Kc[r0 * 64 + sw0] = kr0;
        *(ushortx8*)&Kc[r1 * 64 + sw1] = kr1;
        *(ushortx8*)&Vc[r0 * 64 + sw0] = vr0;
        *(ushortx8*)&Vc[r1 * 64 + sw1] = vr1;
        __syncthreads();

        if (kt < ext) {
            const int s1 = (kt + 1) * 64;
            kr0 = *(const ushortx8*)&Kg[(size_t)(s1 + r0) * HS_ + c0 * 8];
            kr1 = *(const ushortx8*)&Kg[(size_t)(s1 + r1) * HS_ + c1 * 8];
            vr0 = *(const ushortx8*)&Vg[(size_t)r0 * T_ + s1 + c0 * 8];
            vr1 = *(const ushortx8*)&Vg[(size_t)r1 * T_ + s1 + c1 * 8];
        }

        floatx4 st[4];
        #pragma unroll
        for (int kc = 0; kc < 4; ++kc) {
            const int kb = (kc * 16 + m) * 64;
            bf16x8 k0 = *(const bf16x8*)&Kc[kb + cA];
            bf16x8 k1 = *(const bf16x8*)&Kc[kb + (cA ^ 32)];
            floatx4 a = (floatx4){0.f, 0.f, 0.f, 0.f};
            a = __builtin_amdgcn_mfma_f32_16x16x32_bf16(k0, qf0, a, 0, 0, 0);
            a = __builtin_amdgcn_mfma_f32_16x16x32_bf16(k1, qf1, a, 0, 0, 0);
            st[kc] = a;
        }

        if (kt == ext) {
            #pragma unroll
            for (int kc = 0; kc < 4; ++kc) {
                #pragma unroll
                for (int r = 0; r < 4; ++r)
                    if (kc * 16 + quad * 4 + r > qloc) st[kc][r] = -1e30f;
            }
        }

        float lsum = 0.f;
        #pragma unroll
        for (int kc = 0; kc < 4; ++kc) {
            const float p0 = __expf(st[kc][0]);
            const float p1 = __expf(st[kc][1]);
            const float p2 = __expf(st[kc][2]);
            const float p3 = __expf(st[kc][3]);
            lsum += (p0 + p1) + (p2 + p3);
            uintx2 pk;
            pk[0] = f2bf_pk(p0, p1);
            pk[1] = f2bf_pk(p2, p3);
            *(uintx2*)&Pw[pbase + (((kc * 2 + pcs) ^ pxor) << 3)] = pk;
        }
        l_lane += lsum;

        asm volatile("s_waitcnt lgkmcnt(0)" ::: "memory");
        bf16x8 pf0 = *(const bf16x8*)&Pw[m * 64 + cA];
        bf16x8 pf1 = *(const bf16x8*)&Pw[m * 64 + (cA ^ 32)];

        #pragma unroll
        for (int dt = 0; dt < 4; ++dt) {
            const int vb = (dt * 16 + m) * 64;
            bf16x8 v0 = *(const bf16x8*)&Vc[vb + cA];
            bf16x8 v1 = *(const bf16x8*)&Vc[vb + (cA ^ 32)];
            acc_o[dt] = __builtin_amdgcn_mfma_f32_16x16x32_bf16(v0, pf0, acc_o[dt], 0, 0, 0);
            acc_o[dt] = __builtin_amdgcn_mfma_f32_16x16x32_bf16(v1, pf1, acc_o[dt], 0, 0, 0);
        }
    }

    float ls = l_lane;
    ls += __shfl_xor(ls, 16, 64);
    ls += __shfl_xor(ls, 32, 64);
    const float rcp = 1.0f / ls;

    const int t = rowbase + m;
    ushort_t* __restrict__ cp = ctx + ((size_t)(b * T_) + t) * C_ + h * HS_ + quad * 4;
    #pragma unroll
    for (int dt = 0; dt < 4; ++dt) {
        ushortx4 pk;
        #pragma unroll
        for (int r = 0; r < 4; ++r) pk[r] = f2bf(acc_o[dt][r] * rcp);
        *(ushortx4*)&cp[dt * 16] = pk;
    }
}

// ---------------------------------------------------------------------------
// Launcher. ws (ushorts): Wtq|Wtk|Wtv|Wto | Q | K | Vt | ctx  (~26 MB)
// ---------------------------------------------------------------------------
extern "C" void kernel_launch(void* const* d_in, const int* in_sizes, int n_in,
                              void* d_out, int out_size, void* d_ws, size_t ws_size,
                              hipStream_t stream) {
    const float* x  = (const float*)d_in[0];
    const float* Wq = (const float*)d_in[1];
    const float* bq = (const float*)d_in[2];
    const float* Wk = (const float*)d_in[3];
    const float* bk = (const float*)d_in[4];
    const float* Wv = (const float*)d_in[5];
    const float* bv = (const float*)d_in[6];
    const float* Wo = (const float*)d_in[7];
    const float* bo = (const float*)d_in[8];
    float* out = (float*)d_out;

    const size_t per = (size_t)B_ * NH_ * T_ * HS_;  // 3,145,728
    const size_t wsz = 384 * 384;                    // 147,456
    ushort_t* Wtq = (ushort_t*)d_ws;
    ushort_t* Wtk = Wtq + wsz;
    ushort_t* Wtv = Wtk + wsz;
    ushort_t* Wto = Wtv + wsz;
    ushort_t* Qb  = Wto + wsz;
    ushort_t* Kb  = Qb + per;
    ushort_t* Vtb = Kb + per;
    ushort_t* ctxb = Vtb + per;

    prep<<<dim3(144), 256, 0, stream>>>(Wq, Wk, Wv, Wo, Wtq, Wtk, Wtv, Wto);

    qkv_gemm<<<dim3(M_ / 64, 1152 / 128), 256, 0, stream>>>(
        x, Wtq, Wtk, Wtv, bq, bk, bv, Qb, Kb, Vtb);

    attn_mfma<<<dim3(32, NH_, B_), 256, 0, stream>>>(Qb, Kb, Vtb, ctxb);

    proj_gemm<<<dim3(M_ / 64, 384 / 64), 256, 0, stream>>>(ctxb, Wto, bo, out);
}